// Round 1
// baseline (606.582 us; speedup 1.0000x reference)
//
#include <hip/hip_runtime.h>
#include <cmath>

// DDSP decoder, bit-exact-phase implementation.
// Phase path replicates JAX's fp32 arithmetic exactly:
//  - lin_interp / nearest_interp index+weight math in fp32 with __f*_rn
//  - per-partial increments freq_up/SR in fp32
//  - cumsum as lax.associative_scan (Brent-Kung DAG), reproduced bit-for-bit
//  - phase*2pi in fp32, then sin of that exact fp32 value (f64 reduction)
// Noise path: mean(lin_interp)==mean (exact), irfft(rfft*filt) == circular
// conv with smooth symmetric kernel h, truncated to +-1024 taps.

#define NBATCH 8
#define NT     500
#define ND     128
#define TAUD   88000
#define NPART  64
#define NBINS  256
#define NFREQ  44001
#define LCONV  1024

namespace {

constexpr float  SCALE_TA = (float)(500.0 / 88000.0);   // lin_interp scale, fp32 like jnp
constexpr float  SCALE_NF = (float)(256.0 / 44001.0);
constexpr float  TWOPI_F  = (float)6.283185307179586476925286766559;
constexpr double TWOPI_D  = 6.283185307179586476925286766559;
constexpr double INV2PI_D = 0.159154943091895335768883763373;

__device__ __forceinline__ void iparams(int j, int& i0, int& i1, float& w) {
  float jf  = (float)j;
  float src = __fsub_rn(__fmul_rn(__fadd_rn(jf, 0.5f), SCALE_TA), 0.5f);
  src = fminf(fmaxf(src, 0.0f), 499.0f);
  int a = (int)src;            // floor (src >= 0)
  i0 = a;
  i1 = (a + 1 > 499) ? 499 : (a + 1);
  w  = __fsub_rn(src, (float)a);
}

__device__ __forceinline__ float inc_val(const float* sf0, int j, float pf) {
  int i0, i1; float w;
  iparams(j, i0, i1, w);
  float fa = __fmul_rn(sf0[i0], pf);
  float fb = __fmul_rn(sf0[i1], pf);
  float fu = __fadd_rn(__fmul_rn(fa, __fsub_rn(1.0f, w)), __fmul_rn(fb, w));
  return __fdiv_rn(fu, 44100.0f);
}

// sin of the exact fp32 value x (|x| up to ~3e5), matching libm sinf
__device__ __forceinline__ float sin_ref(float x) {
  double xd = (double)x;
  double k  = rint(xd * INV2PI_D);
  double r  = fma(-k, TWOPI_D, xd);
  return sinf((float)r);
}

// ---------------- f0 (Hz) ----------------
__global__ __launch_bounds__(256) void k_f0(const float* __restrict__ f0n,
                                            float* __restrict__ f0hz,
                                            float C1, float C2) {
  int i = blockIdx.x * 256 + threadIdx.x;
  if (i < NBATCH * NT) {
    float x = __fadd_rn(__fmul_rn(f0n[i], C1), C2);
    f0hz[i] = (float)exp2((double)x);
  }
}

// ---------------- MLP heads (8 rows / block) ----------------
__global__ __launch_bounds__(256) void k_mlp(
    const float* __restrict__ z,
    const float* __restrict__ W1p, const float* __restrict__ b1p,
    const float* __restrict__ W2p, const float* __restrict__ b2p,
    const float* __restrict__ W1n, const float* __restrict__ b1n,
    const float* __restrict__ W2n, const float* __restrict__ b2n,
    float* __restrict__ amp, float* __restrict__ nmag) {
  int row0 = blockIdx.x * 8;
  int tid  = threadIdx.x;
  __shared__ float zs[8][ND];
  __shared__ float hp[8][256];
  __shared__ float hn[8][256];
  for (int i = tid; i < 8 * ND; i += 256) {
    int r = i >> 7, d = i & 127;
    zs[r][d] = z[(size_t)(row0 + r) * ND + d];
  }
  __syncthreads();
  float ap[8], an[8];
  float bp = b1p[tid], bn = b1n[tid];
#pragma unroll
  for (int r = 0; r < 8; ++r) { ap[r] = bp; an[r] = bn; }
  for (int d = 0; d < ND; ++d) {
    float w1 = W1p[d * 256 + tid];
    float w2 = W1n[d * 256 + tid];
#pragma unroll
    for (int r = 0; r < 8; ++r) {
      float zz = zs[r][d];
      ap[r] = fmaf(zz, w1, ap[r]);
      an[r] = fmaf(zz, w2, an[r]);
    }
  }
#pragma unroll
  for (int r = 0; r < 8; ++r) {
    hp[r][tid] = fmaxf(ap[r], 0.0f);
    hn[r][tid] = fmaxf(an[r], 0.0f);
  }
  __syncthreads();
  // noise-mags head (256 outputs)
  float a2[8];
  float bn2 = b2n[tid];
#pragma unroll
  for (int r = 0; r < 8; ++r) a2[r] = bn2;
  for (int h = 0; h < 256; ++h) {
    float w = W2n[h * 256 + tid];
#pragma unroll
    for (int r = 0; r < 8; ++r) a2[r] = fmaf(hn[r][h], w, a2[r]);
  }
#pragma unroll
  for (int r = 0; r < 8; ++r)
    nmag[(size_t)(row0 + r) * 256 + tid] = 1.0f / (1.0f + expf(-a2[r]));
  // amp head (64 outputs)
  if (tid < 64) {
    float a1[8];
    float bp2 = b2p[tid];
#pragma unroll
    for (int r = 0; r < 8; ++r) a1[r] = bp2;
    for (int h = 0; h < 256; ++h) {
      float w = W2p[h * 64 + tid];
#pragma unroll
      for (int r = 0; r < 8; ++r) a1[r] = fmaf(hp[r][h], w, a1[r]);
    }
#pragma unroll
    for (int r = 0; r < 8; ++r)
      amp[(size_t)(row0 + r) * 64 + tid] = 1.0f / (1.0f + expf(-a1[r]));
  }
}

// ---------------- mean over frames (== mean of lin_interp, exact) ----------------
__global__ __launch_bounds__(256) void k_mean(const float* __restrict__ nmag,
                                              float* __restrict__ mm) {
  int b = blockIdx.x, k = threadIdx.x;
  float s = 0.0f;
  for (int t = 0; t < NT; ++t) s += nmag[((size_t)b * NT + t) * 256 + k];
  mm[b * 256 + k] = s * (1.0f / 500.0f);
}

// ---------------- filter spectrum F (B, 44001) ----------------
__global__ __launch_bounds__(256) void k_filt(const float* __restrict__ mm,
                                              float* __restrict__ F) {
  int idx = blockIdx.x * 256 + threadIdx.x;
  if (idx >= NBATCH * NFREQ) return;
  int b = idx / NFREQ, k = idx - b * NFREQ;
  float kf  = (float)k;
  float src = __fsub_rn(__fmul_rn(__fadd_rn(kf, 0.5f), SCALE_NF), 0.5f);
  src = fminf(fmaxf(src, 0.0f), 255.0f);
  int i0 = (int)src;
  int i1 = (i0 + 1 > 255) ? 255 : (i0 + 1);
  float w = __fsub_rn(src, (float)i0);
  F[idx] = __fadd_rn(__fmul_rn(mm[b * 256 + i0], __fsub_rn(1.0f, w)),
                     __fmul_rn(mm[b * 256 + i1], w));
}

// ---------------- cumsum top levels: Brent-Kung (associative_scan DAG) ----------------
// levels: L4=5500, L5=2750, L6=1375, L7=687, L8=343, L9=171, L10=85, L11=42,
//         L12=21, L13=10, L14=5, L15=2, L16=1    (odd-level stragglers unpaired)
__global__ __launch_bounds__(256) void k_scan_top(const float* __restrict__ f0hz,
                                                  float* __restrict__ pref4) {
  int bp = blockIdx.x;
  int b = bp >> 6, p = bp & 63;
  float pf = (float)(p + 1);
  __shared__ float sf0[NT];
  __shared__ float lev[10992];
  int tid = threadIdx.x;
  for (int i = tid; i < NT; i += 256) sf0[i] = f0hz[b * NT + i];
  __syncthreads();
  // level-4 block sums (16 increments each, exact pair tree)
  for (int m = tid; m < 5500; m += 256) {
    float v[16];
#pragma unroll
    for (int t = 0; t < 16; ++t) v[t] = inc_val(sf0, m * 16 + t, pf);
    float s1[8];
#pragma unroll
    for (int t = 0; t < 8; ++t) s1[t] = __fadd_rn(v[2 * t], v[2 * t + 1]);
    float s2[4];
#pragma unroll
    for (int t = 0; t < 4; ++t) s2[t] = __fadd_rn(s1[2 * t], s1[2 * t + 1]);
    float s3a = __fadd_rn(s2[0], s2[1]);
    float s3b = __fadd_rn(s2[2], s2[3]);
    lev[m] = __fadd_rn(s3a, s3b);
  }
  __syncthreads();
  const int sizes[13] = {5500, 2750, 1375, 687, 343, 171, 85, 42, 21, 10, 5, 2, 1};
  const int offs[13]  = {0, 5500, 8250, 9625, 10312, 10655, 10826, 10911,
                         10953, 10974, 10984, 10989, 10991};
  // upsweep
  for (int L = 1; L < 13; ++L) {
    int n = sizes[L];
    const float* src = lev + offs[L - 1];
    float* dst = lev + offs[L];
    for (int k2 = tid; k2 < n; k2 += 256)
      dst[k2] = __fadd_rn(src[2 * k2], src[2 * k2 + 1]);
    __syncthreads();
  }
  // downsweep (in place): pref[0]=s[0]; pref[2k+1]=up[k]; pref[2k+2]=up[k]+s[2k+2]
  for (int L = 11; L >= 0; --L) {
    int n = sizes[L];
    float* cur = lev + offs[L];
    const float* up = lev + offs[L + 1];
    for (int idx = 1 + tid; idx < n; idx += 256) {
      float val;
      if (idx & 1) val = up[(idx - 1) >> 1];
      else         val = __fadd_rn(up[(idx >> 1) - 1], cur[idx]);
      cur[idx] = val;
    }
    __syncthreads();
  }
  for (int m = tid; m < 5500; m += 256)
    pref4[(size_t)bp * 5500 + m] = lev[m];
}

// ---------------- fused harmonic synth ----------------
// grid (chunk=22, b=8, g=4); thread owns one 16-sample block; loops 16 partials
__global__ __launch_bounds__(256) void k_harm(const float* __restrict__ f0hz,
                                              const float* __restrict__ amp,
                                              const float* __restrict__ pref4,
                                              float* __restrict__ hpart) {
  int chunk = blockIdx.x, b = blockIdx.y, g = blockIdx.z;
  int tid = threadIdx.x;
  int m = chunk * 256 + tid;
  bool act = (m < 5500);
  __shared__ float sf0[NT];
  for (int i = tid; i < NT; i += 256) sf0[i] = f0hz[b * NT + i];
  __syncthreads();
  int mm_ = act ? m : 0;
  int j0 = mm_ * 16;
  int i0a[16]; float wv[16]; int nidx[16];
#pragma unroll
  for (int t = 0; t < 16; ++t) {
    int j = j0 + t;
    float jf = (float)j;
    float src = __fsub_rn(__fmul_rn(__fadd_rn(jf, 0.5f), SCALE_TA), 0.5f);
    src = fminf(fmaxf(src, 0.0f), 499.0f);
    int a = (int)src;
    i0a[t] = a;
    wv[t] = __fsub_rn(src, (float)a);
    int ni = (int)__fmul_rn(jf, SCALE_TA);
    nidx[t] = ni > 499 ? 499 : ni;
  }
  float acc[16];
#pragma unroll
  for (int t = 0; t < 16; ++t) acc[t] = 0.0f;

  for (int pp = 0; pp < 16; ++pp) {
    int p = g * 16 + pp;
    float pf = (float)(p + 1);
    size_t pbase = ((size_t)(b * NPART + p)) * 5500;
    float left = (mm_ > 0) ? pref4[pbase + mm_ - 1] : 0.0f;
    float P4 = pref4[pbase + mm_];
    float v[16];
#pragma unroll
    for (int t = 0; t < 16; ++t) {
      int i0 = i0a[t];
      int i1 = (i0 + 1 > 499) ? 499 : (i0 + 1);
      float w = wv[t];
      float fa = __fmul_rn(sf0[i0], pf);
      float fb = __fmul_rn(sf0[i1], pf);
      float fu = __fadd_rn(__fmul_rn(fa, __fsub_rn(1.0f, w)), __fmul_rn(fb, w));
      v[t] = __fdiv_rn(fu, 44100.0f);
    }
    float s1[8];
#pragma unroll
    for (int t = 0; t < 8; ++t) s1[t] = __fadd_rn(v[2 * t], v[2 * t + 1]);
    float s2[4];
#pragma unroll
    for (int t = 0; t < 4; ++t) s2[t] = __fadd_rn(s1[2 * t], s1[2 * t + 1]);
    float s3_0 = __fadd_rn(s2[0], s2[1]);
    bool fz = (mm_ == 0);
    // local downsweep of the global DAG within this 16-block
    float l3_0 = fz ? s3_0 : __fadd_rn(left, s3_0);
    float l2_0 = fz ? s2[0] : __fadd_rn(left, s2[0]);
    float l2_1 = l3_0;
    float l2_2 = __fadd_rn(l3_0, s2[2]);
    float l2_3 = P4;
    float l1_0 = fz ? s1[0] : __fadd_rn(left, s1[0]);
    float l1_1 = l2_0;
    float l1_2 = __fadd_rn(l2_0, s1[2]);
    float l1_3 = l2_1;
    float l1_4 = __fadd_rn(l2_1, s1[4]);
    float l1_5 = l2_2;
    float l1_6 = __fadd_rn(l2_2, s1[6]);
    float l1_7 = l2_3;
    float ph[16];
    ph[0]  = fz ? v[0] : __fadd_rn(left, v[0]);
    ph[1]  = l1_0;
    ph[2]  = __fadd_rn(l1_0, v[2]);
    ph[3]  = l1_1;
    ph[4]  = __fadd_rn(l1_1, v[4]);
    ph[5]  = l1_2;
    ph[6]  = __fadd_rn(l1_2, v[6]);
    ph[7]  = l1_3;
    ph[8]  = __fadd_rn(l1_3, v[8]);
    ph[9]  = l1_4;
    ph[10] = __fadd_rn(l1_4, v[10]);
    ph[11] = l1_5;
    ph[12] = __fadd_rn(l1_5, v[12]);
    ph[13] = l1_6;
    ph[14] = __fadd_rn(l1_6, v[14]);
    ph[15] = l1_7;
#pragma unroll
    for (int t = 0; t < 16; ++t) {
      float fr = __fmul_rn(sf0[nidx[t]], pf);
      if (fr < 22050.0f) {
        float x = __fmul_rn(ph[t], TWOPI_F);
        float s = sin_ref(x);
        int i0 = i0a[t];
        int i1 = (i0 + 1 > 499) ? 499 : (i0 + 1);
        float w = wv[t];
        float a0 = amp[((size_t)(b * NT + i0)) * 64 + p];
        float a1 = amp[((size_t)(b * NT + i1)) * 64 + p];
        float au = __fadd_rn(__fmul_rn(a0, __fsub_rn(1.0f, w)), __fmul_rn(a1, w));
        acc[t] = __fadd_rn(acc[t], __fmul_rn(s, au));
      }
    }
  }
  if (act) {
    size_t obase = ((size_t)g * NBATCH + b) * TAUD + (size_t)j0;
#pragma unroll
    for (int t = 0; t < 16; ++t) hpart[obase + t] = acc[t];
  }
}

// ---------------- noise filter impulse response h[0..LCONV] ----------------
__global__ __launch_bounds__(256) void k_h(const float* __restrict__ F,
                                           float* __restrict__ hh) {
  int n = blockIdx.x;  // 0..LCONV
  int b = blockIdx.y;
  int tid = threadIdx.x;
  const float C = (float)(6.283185307179586476925286766559 / 88000.0);
  long long step = ((long long)n * 256) % TAUD;
  long long mcur = ((long long)n * (1 + tid)) % TAUD;
  float s = 0.0f;
  for (int k = 1 + tid; k < TAUD / 2; k += 256) {
    s = fmaf(F[(size_t)b * NFREQ + k], __cosf((float)mcur * C), s);
    mcur += step;
    if (mcur >= TAUD) mcur -= TAUD;
  }
  __shared__ float red[256];
  red[tid] = s;
  __syncthreads();
  for (int st = 128; st > 0; st >>= 1) {
    if (tid < st) red[tid] += red[tid + st];
    __syncthreads();
  }
  if (tid == 0) {
    float F0 = F[(size_t)b * NFREQ + 0];
    float FN = F[(size_t)b * NFREQ + TAUD / 2];
    float tot = 2.0f * red[0] + F0 + ((n & 1) ? -FN : FN);
    hh[b * (LCONV + 1) + n] = tot * (1.0f / 88000.0f);
  }
}

// ---------------- circular convolution (truncated +-LCONV) ----------------
__global__ __launch_bounds__(256) void k_conv(const float* __restrict__ noise,
                                              const float* __restrict__ hh,
                                              float* __restrict__ ynz) {
  int b = blockIdx.y;
  int t0 = blockIdx.x * 256;
  int tid = threadIdx.x;
  __shared__ float xs[256 + 2 * LCONV];
  __shared__ float hs[LCONV + 1];
  for (int i = tid; i < LCONV + 1; i += 256) hs[i] = hh[b * (LCONV + 1) + i];
  for (int i = tid; i < 256 + 2 * LCONV; i += 256) {
    int j = t0 - LCONV + i;
    if (j < 0) j += TAUD;
    else if (j >= TAUD) j -= TAUD;
    xs[i] = noise[(size_t)b * TAUD + j];
  }
  __syncthreads();
  int t = t0 + tid;
  if (t >= TAUD) return;
  float acc = hs[0] * xs[LCONV + tid];
#pragma unroll 4
  for (int d = 1; d <= LCONV; ++d)
    acc = fmaf(hs[d], xs[LCONV + tid - d] + xs[LCONV + tid + d], acc);
  ynz[(size_t)b * TAUD + t] = acc * 0.1f;
}

// ---------------- final mix ----------------
__global__ __launch_bounds__(256) void k_final(const float* __restrict__ hpart,
                                               const float* __restrict__ ynz,
                                               const float* __restrict__ loud,
                                               float* __restrict__ out) {
  int idx = blockIdx.x * 256 + threadIdx.x;
  if (idx >= NBATCH * TAUD) return;
  int b = idx / TAUD, j = idx - b * TAUD;
  int i0, i1; float w;
  iparams(j, i0, i1, w);
  float env = __fadd_rn(__fmul_rn(loud[b * NT + i0], __fsub_rn(1.0f, w)),
                        __fmul_rn(loud[b * NT + i1], w));
  const size_t S = (size_t)NBATCH * TAUD;
  float hsum = __fadd_rn(__fadd_rn(__fadd_rn(hpart[idx], hpart[S + idx]),
                                   hpart[2 * S + idx]),
                         hpart[3 * S + idx]);
  out[idx] = __fmul_rn(__fadd_rn(hsum, ynz[idx]), env);
}

}  // namespace

extern "C" void kernel_launch(void* const* d_in, const int* in_sizes, int n_in,
                              void* d_out, int out_size, void* d_ws, size_t ws_size,
                              hipStream_t stream) {
  const float* z    = (const float*)d_in[0];
  const float* f0n  = (const float*)d_in[1];
  const float* loud = (const float*)d_in[2];
  const float* nz   = (const float*)d_in[3];
  const float* W1p  = (const float*)d_in[4];
  const float* b1p  = (const float*)d_in[5];
  const float* W2p  = (const float*)d_in[6];
  const float* b2p  = (const float*)d_in[7];
  const float* W1n  = (const float*)d_in[8];
  const float* b1n  = (const float*)d_in[9];
  const float* W2n  = (const float*)d_in[10];
  const float* b2n  = (const float*)d_in[11];
  float* out = (float*)d_out;
  float* ws  = (float*)d_ws;

  size_t off = 0;
  float* amp   = ws + off; off += (size_t)NBATCH * NT * NPART;      // 256,000
  float* nmag  = ws + off; off += (size_t)NBATCH * NT * NBINS;      // 1,024,000
  float* f0hz  = ws + off; off += (size_t)NBATCH * NT;              // 4,000
  float* mm    = ws + off; off += (size_t)NBATCH * NBINS;           // 2,048
  float* F     = ws + off; off += (size_t)NBATCH * NFREQ;           // 352,008
  float* hh    = ws + off; off += (size_t)NBATCH * (LCONV + 1);     // 8,200
  float* ynz   = ws + off; off += (size_t)NBATCH * TAUD;            // 704,000
  float* pref4 = ws + off; off += (size_t)NBATCH * NPART * 5500;    // 2,816,000
  float* hpart = ws + off; off += (size_t)4 * NBATCH * TAUD;        // 2,816,000
  (void)ws_size; (void)in_sizes; (void)n_in; (void)out_size;        // ~30.5 MB total

  // f0 constants exactly as the reference's python-float -> fp32 promotion
  double HI = log2(2093.0), LO = log2(32.7);
  float C1 = (float)(HI - LO), C2 = (float)LO;

  k_f0<<<(NBATCH * NT + 255) / 256, 256, 0, stream>>>(f0n, f0hz, C1, C2);
  k_mlp<<<(NBATCH * NT) / 8, 256, 0, stream>>>(z, W1p, b1p, W2p, b2p,
                                               W1n, b1n, W2n, b2n, amp, nmag);
  k_mean<<<NBATCH, 256, 0, stream>>>(nmag, mm);
  k_filt<<<(NBATCH * NFREQ + 255) / 256, 256, 0, stream>>>(mm, F);
  k_scan_top<<<NBATCH * NPART, 256, 0, stream>>>(f0hz, pref4);
  dim3 gh(22, NBATCH, 4);
  k_harm<<<gh, 256, 0, stream>>>(f0hz, amp, pref4, hpart);
  dim3 gk(LCONV + 1, NBATCH);
  k_h<<<gk, 256, 0, stream>>>(F, hh);
  dim3 gc((TAUD + 255) / 256, NBATCH);
  k_conv<<<gc, 256, 0, stream>>>(nz, hh, ynz);
  k_final<<<(NBATCH * TAUD + 255) / 256, 256, 0, stream>>>(hpart, ynz, loud, out);
}

// Round 2
// 395.330 us; speedup vs baseline: 1.5344x; 1.5344x over previous
//
#include <hip/hip_runtime.h>
#include <cmath>

// DDSP decoder, bit-exact-phase implementation.
// R2: replace per-batch direct-DFT k_h (240us) with batch-independent basis
//     G[n][i] (4x less work) + tiny per-batch combine; hoist k_harm's
//     per-partial LDS/global re-reads into registers (bit-identical selects).

#define NBATCH 8
#define NT     500
#define ND     128
#define TAUD   88000
#define NPART  64
#define NBINS  256
#define NFREQ  44001
#define LCONV  1024

namespace {

constexpr float  SCALE_TA = (float)(500.0 / 88000.0);   // lin_interp scale, fp32 like jnp
constexpr float  SCALE_NF = (float)(256.0 / 44001.0);
constexpr float  TWOPI_F  = (float)6.283185307179586476925286766559;
constexpr double TWOPI_D  = 6.283185307179586476925286766559;
constexpr double INV2PI_D = 0.159154943091895335768883763373;
constexpr float  CANG     = (float)(6.283185307179586476925286766559 / 88000.0);

__device__ __forceinline__ void iparams(int j, int& i0, int& i1, float& w) {
  float jf  = (float)j;
  float src = __fsub_rn(__fmul_rn(__fadd_rn(jf, 0.5f), SCALE_TA), 0.5f);
  src = fminf(fmaxf(src, 0.0f), 499.0f);
  int a = (int)src;            // floor (src >= 0)
  i0 = a;
  i1 = (a + 1 > 499) ? 499 : (a + 1);
  w  = __fsub_rn(src, (float)a);
}

__device__ __forceinline__ float inc_val(const float* sf0, int j, float pf) {
  int i0, i1; float w;
  iparams(j, i0, i1, w);
  float fa = __fmul_rn(sf0[i0], pf);
  float fb = __fmul_rn(sf0[i1], pf);
  float fu = __fadd_rn(__fmul_rn(fa, __fsub_rn(1.0f, w)), __fmul_rn(fb, w));
  return __fdiv_rn(fu, 44100.0f);
}

// sin of the exact fp32 value x (|x| up to ~3e5), matching libm sinf
__device__ __forceinline__ float sin_ref(float x) {
  double xd = (double)x;
  double k  = rint(xd * INV2PI_D);
  double r  = fma(-k, TWOPI_D, xd);
  return sinf((float)r);
}

// ---------------- f0 (Hz) ----------------
__global__ __launch_bounds__(256) void k_f0(const float* __restrict__ f0n,
                                            float* __restrict__ f0hz,
                                            float C1, float C2) {
  int i = blockIdx.x * 256 + threadIdx.x;
  if (i < NBATCH * NT) {
    float x = __fadd_rn(__fmul_rn(f0n[i], C1), C2);
    f0hz[i] = (float)exp2((double)x);
  }
}

// ---------------- MLP heads (8 rows / block) ----------------
__global__ __launch_bounds__(256) void k_mlp(
    const float* __restrict__ z,
    const float* __restrict__ W1p, const float* __restrict__ b1p,
    const float* __restrict__ W2p, const float* __restrict__ b2p,
    const float* __restrict__ W1n, const float* __restrict__ b1n,
    const float* __restrict__ W2n, const float* __restrict__ b2n,
    float* __restrict__ amp, float* __restrict__ nmag) {
  int row0 = blockIdx.x * 8;
  int tid  = threadIdx.x;
  __shared__ float zs[8][ND];
  __shared__ float hp[8][256];
  __shared__ float hn[8][256];
  for (int i = tid; i < 8 * ND; i += 256) {
    int r = i >> 7, d = i & 127;
    zs[r][d] = z[(size_t)(row0 + r) * ND + d];
  }
  __syncthreads();
  float ap[8], an[8];
  float bp = b1p[tid], bn = b1n[tid];
#pragma unroll
  for (int r = 0; r < 8; ++r) { ap[r] = bp; an[r] = bn; }
  for (int d = 0; d < ND; ++d) {
    float w1 = W1p[d * 256 + tid];
    float w2 = W1n[d * 256 + tid];
#pragma unroll
    for (int r = 0; r < 8; ++r) {
      float zz = zs[r][d];
      ap[r] = fmaf(zz, w1, ap[r]);
      an[r] = fmaf(zz, w2, an[r]);
    }
  }
#pragma unroll
  for (int r = 0; r < 8; ++r) {
    hp[r][tid] = fmaxf(ap[r], 0.0f);
    hn[r][tid] = fmaxf(an[r], 0.0f);
  }
  __syncthreads();
  // noise-mags head (256 outputs)
  float a2[8];
  float bn2 = b2n[tid];
#pragma unroll
  for (int r = 0; r < 8; ++r) a2[r] = bn2;
  for (int h = 0; h < 256; ++h) {
    float w = W2n[h * 256 + tid];
#pragma unroll
    for (int r = 0; r < 8; ++r) a2[r] = fmaf(hn[r][h], w, a2[r]);
  }
#pragma unroll
  for (int r = 0; r < 8; ++r)
    nmag[(size_t)(row0 + r) * 256 + tid] = 1.0f / (1.0f + expf(-a2[r]));
  // amp head (64 outputs)
  if (tid < 64) {
    float a1[8];
    float bp2 = b2p[tid];
#pragma unroll
    for (int r = 0; r < 8; ++r) a1[r] = bp2;
    for (int h = 0; h < 256; ++h) {
      float w = W2p[h * 64 + tid];
#pragma unroll
      for (int r = 0; r < 8; ++r) a1[r] = fmaf(hp[r][h], w, a1[r]);
    }
#pragma unroll
    for (int r = 0; r < 8; ++r)
      amp[(size_t)(row0 + r) * 64 + tid] = 1.0f / (1.0f + expf(-a1[r]));
  }
}

// ---------------- mean over frames (== mean of lin_interp, exact) ----------------
__global__ __launch_bounds__(256) void k_mean(const float* __restrict__ nmag,
                                              float* __restrict__ mm) {
  int b = blockIdx.x, k = threadIdx.x;
  float s = 0.0f;
  for (int t = 0; t < NT; ++t) s += nmag[((size_t)b * NT + t) * 256 + k];
  mm[b * 256 + k] = s * (1.0f / 500.0f);
}

// ---------------- basis G[n][i] = sum_k hat_i(k) * cos(2 pi n k / 88000) ----------------
// input-independent; hat support ~344 bins per (n,i). k range [1, 43999].
__global__ __launch_bounds__(256) void k_basis(float* __restrict__ G) {
  int n = blockIdx.x;       // 0..1024
  int i = threadIdx.x;      // bin 0..255
  // window covering all k with i0(k) in {i-1, i} (fp32 boundary margin +-4)
  int start = 1, end = 43999;
  if (i > 0) {
    int s0 = (int)(((float)i - 0.5f) * 171.87890625f - 0.5f) - 4;
    if (s0 > start) start = s0;
  }
  int e0 = (int)(((float)i + 1.5f) * 171.87890625f - 0.5f) + 4;
  if (e0 < end) end = e0;
  float acc = 0.0f;
  int m = (n * start) % TAUD;
  for (int k = start; k <= end; ++k) {
    float kf  = (float)k;
    float src = __fsub_rn(__fmul_rn(__fadd_rn(kf, 0.5f), SCALE_NF), 0.5f);
    src = fminf(fmaxf(src, 0.0f), 255.0f);
    int i0 = (int)src;
    float w = __fsub_rn(src, (float)i0);
    float wt = 0.0f;
    if (i0 == i) wt = __fsub_rn(1.0f, w);
    int i1 = (i0 < 255) ? i0 + 1 : 255;
    if (i1 == i) wt = __fadd_rn(wt, w);
    acc = fmaf(wt, __cosf((float)m * CANG), acc);
    m += n; if (m >= TAUD) m -= TAUD;
  }
  G[n * 256 + i] = acc;
}

// ---------------- combine: h[b][n] = (F0 +- FN + 2*sum_i mm_i G[n][i]) / N ----------------
__global__ __launch_bounds__(256) void k_hc(const float* __restrict__ mm,
                                            const float* __restrict__ G,
                                            float* __restrict__ hh) {
  int n = blockIdx.x;       // 0..1024
  int tid = threadIdx.x;
  float g = G[n * 256 + tid];
  __shared__ float red[256];
  for (int b = 0; b < NBATCH; ++b) {
    red[tid] = mm[b * 256 + tid] * g;
    __syncthreads();
    for (int st = 128; st > 0; st >>= 1) {
      if (tid < st) red[tid] += red[tid + st];
      __syncthreads();
    }
    if (tid == 0) {
      float F0 = mm[b * 256 + 0];
      // F at k = 44000 (reference interp formula)
      float src = __fsub_rn(__fmul_rn(__fadd_rn(44000.0f, 0.5f), SCALE_NF), 0.5f);
      src = fminf(fmaxf(src, 0.0f), 255.0f);
      int i0 = (int)src;
      float w = __fsub_rn(src, (float)i0);
      int i1 = (i0 < 255) ? i0 + 1 : 255;
      float FN = __fadd_rn(__fmul_rn(mm[b * 256 + i0], __fsub_rn(1.0f, w)),
                           __fmul_rn(mm[b * 256 + i1], w));
      float tot = 2.0f * red[0] + F0 + ((n & 1) ? -FN : FN);
      hh[b * (LCONV + 1) + n] = tot * (1.0f / 88000.0f);
    }
    __syncthreads();
  }
}

// ---------------- cumsum top levels: Brent-Kung (associative_scan DAG) ----------------
__global__ __launch_bounds__(256) void k_scan_top(const float* __restrict__ f0hz,
                                                  float* __restrict__ pref4) {
  int bp = blockIdx.x;
  int b = bp >> 6, p = bp & 63;
  float pf = (float)(p + 1);
  __shared__ float sf0[NT];
  __shared__ float lev[10992];
  int tid = threadIdx.x;
  for (int i = tid; i < NT; i += 256) sf0[i] = f0hz[b * NT + i];
  __syncthreads();
  for (int m = tid; m < 5500; m += 256) {
    float v[16];
#pragma unroll
    for (int t = 0; t < 16; ++t) v[t] = inc_val(sf0, m * 16 + t, pf);
    float s1[8];
#pragma unroll
    for (int t = 0; t < 8; ++t) s1[t] = __fadd_rn(v[2 * t], v[2 * t + 1]);
    float s2[4];
#pragma unroll
    for (int t = 0; t < 4; ++t) s2[t] = __fadd_rn(s1[2 * t], s1[2 * t + 1]);
    float s3a = __fadd_rn(s2[0], s2[1]);
    float s3b = __fadd_rn(s2[2], s2[3]);
    lev[m] = __fadd_rn(s3a, s3b);
  }
  __syncthreads();
  const int sizes[13] = {5500, 2750, 1375, 687, 343, 171, 85, 42, 21, 10, 5, 2, 1};
  const int offs[13]  = {0, 5500, 8250, 9625, 10312, 10655, 10826, 10911,
                         10953, 10974, 10984, 10989, 10991};
  for (int L = 1; L < 13; ++L) {
    int n = sizes[L];
    const float* src = lev + offs[L - 1];
    float* dst = lev + offs[L];
    for (int k2 = tid; k2 < n; k2 += 256)
      dst[k2] = __fadd_rn(src[2 * k2], src[2 * k2 + 1]);
    __syncthreads();
  }
  for (int L = 11; L >= 0; --L) {
    int n = sizes[L];
    float* cur = lev + offs[L];
    const float* up = lev + offs[L + 1];
    for (int idx = 1 + tid; idx < n; idx += 256) {
      float val;
      if (idx & 1) val = up[(idx - 1) >> 1];
      else         val = __fadd_rn(up[(idx >> 1) - 1], cur[idx]);
      cur[idx] = val;
    }
    __syncthreads();
  }
  for (int m = tid; m < 5500; m += 256)
    pref4[(size_t)bp * 5500 + m] = lev[m];
}

// ---------------- fused harmonic synth ----------------
// grid (chunk=22, b=8, g=4); thread owns one 16-sample block; loops 16 partials.
// Frame index spans at most 2 values within a 16-sample block -> hoist the
// f0/amp loads to 3 registers; selects are bit-identical to indexed loads.
__global__ __launch_bounds__(256) void k_harm(const float* __restrict__ f0hz,
                                              const float* __restrict__ amp,
                                              const float* __restrict__ pref4,
                                              float* __restrict__ hpart) {
  int chunk = blockIdx.x, b = blockIdx.y, g = blockIdx.z;
  int tid = threadIdx.x;
  int m = chunk * 256 + tid;
  bool act = (m < 5500);
  __shared__ float sf0[NT];
  for (int i = tid; i < NT; i += 256) sf0[i] = f0hz[b * NT + i];
  __syncthreads();
  int mm_ = act ? m : 0;
  int j0 = mm_ * 16;
  float wv[16];
  unsigned damask = 0, dnmask = 0;
  int f = 0;
#pragma unroll
  for (int t = 0; t < 16; ++t) {
    int j = j0 + t;
    float jf = (float)j;
    float src = __fsub_rn(__fmul_rn(__fadd_rn(jf, 0.5f), SCALE_TA), 0.5f);
    src = fminf(fmaxf(src, 0.0f), 499.0f);
    int a = (int)src;
    if (t == 0) f = a;                 // i0 monotone nondecreasing in j
    wv[t] = __fsub_rn(src, (float)a);
    damask |= (unsigned)(a - f) << t;  // in {0,1}
    int ni = (int)__fmul_rn(jf, SCALE_TA);
    ni = ni > 499 ? 499 : ni;
    dnmask |= (unsigned)(ni - f) << t; // in {0,1}
  }
  int f1 = (f + 1 > 499) ? 499 : f + 1;
  int f2 = (f + 2 > 499) ? 499 : f + 2;
  float s0 = sf0[f], s1 = sf0[f1], s2 = sf0[f2];

  float acc[16];
#pragma unroll
  for (int t = 0; t < 16; ++t) acc[t] = 0.0f;

  for (int pp = 0; pp < 16; ++pp) {
    int p = g * 16 + pp;
    float pf = (float)(p + 1);
    size_t pbase = ((size_t)(b * NPART + p)) * 5500;
    float left = (mm_ > 0) ? pref4[pbase + mm_ - 1] : 0.0f;
    float P4 = pref4[pbase + mm_];
    float fs0 = __fmul_rn(s0, pf);
    float fs1 = __fmul_rn(s1, pf);
    float fs2 = __fmul_rn(s2, pf);
    float v[16];
#pragma unroll
    for (int t = 0; t < 16; ++t) {
      bool d = (damask >> t) & 1;
      float fa = d ? fs1 : fs0;
      float fb = d ? fs2 : fs1;
      float w = wv[t];
      float fu = __fadd_rn(__fmul_rn(fa, __fsub_rn(1.0f, w)), __fmul_rn(fb, w));
      v[t] = __fdiv_rn(fu, 44100.0f);
    }
    float s1t[8];
#pragma unroll
    for (int t = 0; t < 8; ++t) s1t[t] = __fadd_rn(v[2 * t], v[2 * t + 1]);
    float s2t[4];
#pragma unroll
    for (int t = 0; t < 4; ++t) s2t[t] = __fadd_rn(s1t[2 * t], s1t[2 * t + 1]);
    float s3_0 = __fadd_rn(s2t[0], s2t[1]);
    bool fz = (mm_ == 0);
    float l3_0 = fz ? s3_0 : __fadd_rn(left, s3_0);
    float l2_0 = fz ? s2t[0] : __fadd_rn(left, s2t[0]);
    float l2_1 = l3_0;
    float l2_2 = __fadd_rn(l3_0, s2t[2]);
    float l2_3 = P4;
    float l1_0 = fz ? s1t[0] : __fadd_rn(left, s1t[0]);
    float l1_1 = l2_0;
    float l1_2 = __fadd_rn(l2_0, s1t[2]);
    float l1_3 = l2_1;
    float l1_4 = __fadd_rn(l2_1, s1t[4]);
    float l1_5 = l2_2;
    float l1_6 = __fadd_rn(l2_2, s1t[6]);
    float l1_7 = l2_3;
    float ph[16];
    ph[0]  = fz ? v[0] : __fadd_rn(left, v[0]);
    ph[1]  = l1_0;
    ph[2]  = __fadd_rn(l1_0, v[2]);
    ph[3]  = l1_1;
    ph[4]  = __fadd_rn(l1_1, v[4]);
    ph[5]  = l1_2;
    ph[6]  = __fadd_rn(l1_2, v[6]);
    ph[7]  = l1_3;
    ph[8]  = __fadd_rn(l1_3, v[8]);
    ph[9]  = l1_4;
    ph[10] = __fadd_rn(l1_4, v[10]);
    ph[11] = l1_5;
    ph[12] = __fadd_rn(l1_5, v[12]);
    ph[13] = l1_6;
    ph[14] = __fadd_rn(l1_6, v[14]);
    ph[15] = l1_7;
    float ga0 = amp[((size_t)(b * NT + f)) * 64 + p];
    float ga1 = amp[((size_t)(b * NT + f1)) * 64 + p];
    float ga2 = amp[((size_t)(b * NT + f2)) * 64 + p];
#pragma unroll
    for (int t = 0; t < 16; ++t) {
      bool dn = (dnmask >> t) & 1;
      float fr = __fmul_rn(dn ? s1 : s0, pf);
      if (fr < 22050.0f) {
        float x = __fmul_rn(ph[t], TWOPI_F);
        float s = sin_ref(x);
        bool d = (damask >> t) & 1;
        float lo = d ? ga1 : ga0;
        float hi = d ? ga2 : ga1;
        float w = wv[t];
        float au = __fadd_rn(__fmul_rn(lo, __fsub_rn(1.0f, w)), __fmul_rn(hi, w));
        acc[t] = __fadd_rn(acc[t], __fmul_rn(s, au));
      }
    }
  }
  if (act) {
    size_t obase = ((size_t)g * NBATCH + b) * TAUD + (size_t)j0;
#pragma unroll
    for (int t = 0; t < 16; ++t) hpart[obase + t] = acc[t];
  }
}

// ---------------- circular convolution (truncated +-LCONV) ----------------
__global__ __launch_bounds__(256) void k_conv(const float* __restrict__ noise,
                                              const float* __restrict__ hh,
                                              float* __restrict__ ynz) {
  int b = blockIdx.y;
  int t0 = blockIdx.x * 256;
  int tid = threadIdx.x;
  __shared__ float xs[256 + 2 * LCONV];
  __shared__ float hs[LCONV + 1];
  for (int i = tid; i < LCONV + 1; i += 256) hs[i] = hh[b * (LCONV + 1) + i];
  for (int i = tid; i < 256 + 2 * LCONV; i += 256) {
    int j = t0 - LCONV + i;
    if (j < 0) j += TAUD;
    else if (j >= TAUD) j -= TAUD;
    xs[i] = noise[(size_t)b * TAUD + j];
  }
  __syncthreads();
  int t = t0 + tid;
  if (t >= TAUD) return;
  float acc = hs[0] * xs[LCONV + tid];
#pragma unroll 4
  for (int d = 1; d <= LCONV; ++d)
    acc = fmaf(hs[d], xs[LCONV + tid - d] + xs[LCONV + tid + d], acc);
  ynz[(size_t)b * TAUD + t] = acc * 0.1f;
}

// ---------------- final mix ----------------
__global__ __launch_bounds__(256) void k_final(const float* __restrict__ hpart,
                                               const float* __restrict__ ynz,
                                               const float* __restrict__ loud,
                                               float* __restrict__ out) {
  int idx = blockIdx.x * 256 + threadIdx.x;
  if (idx >= NBATCH * TAUD) return;
  int b = idx / TAUD, j = idx - b * TAUD;
  int i0, i1; float w;
  iparams(j, i0, i1, w);
  float env = __fadd_rn(__fmul_rn(loud[b * NT + i0], __fsub_rn(1.0f, w)),
                        __fmul_rn(loud[b * NT + i1], w));
  const size_t S = (size_t)NBATCH * TAUD;
  float hsum = __fadd_rn(__fadd_rn(__fadd_rn(hpart[idx], hpart[S + idx]),
                                   hpart[2 * S + idx]),
                         hpart[3 * S + idx]);
  out[idx] = __fmul_rn(__fadd_rn(hsum, ynz[idx]), env);
}

}  // namespace

extern "C" void kernel_launch(void* const* d_in, const int* in_sizes, int n_in,
                              void* d_out, int out_size, void* d_ws, size_t ws_size,
                              hipStream_t stream) {
  const float* z    = (const float*)d_in[0];
  const float* f0n  = (const float*)d_in[1];
  const float* loud = (const float*)d_in[2];
  const float* nz   = (const float*)d_in[3];
  const float* W1p  = (const float*)d_in[4];
  const float* b1p  = (const float*)d_in[5];
  const float* W2p  = (const float*)d_in[6];
  const float* b2p  = (const float*)d_in[7];
  const float* W1n  = (const float*)d_in[8];
  const float* b1n  = (const float*)d_in[9];
  const float* W2n  = (const float*)d_in[10];
  const float* b2n  = (const float*)d_in[11];
  float* out = (float*)d_out;
  float* ws  = (float*)d_ws;

  size_t off = 0;
  float* amp   = ws + off; off += (size_t)NBATCH * NT * NPART;      // 256,000
  float* nmag  = ws + off; off += (size_t)NBATCH * NT * NBINS;      // 1,024,000
  float* f0hz  = ws + off; off += (size_t)NBATCH * NT;              // 4,000
  float* mmw   = ws + off; off += (size_t)NBATCH * NBINS;           // 2,048
  float* G     = ws + off; off += (size_t)(LCONV + 1) * NBINS;      // 262,400
  float* hh    = ws + off; off += (size_t)NBATCH * (LCONV + 1);     // 8,200
  float* ynz   = ws + off; off += (size_t)NBATCH * TAUD;            // 704,000
  float* pref4 = ws + off; off += (size_t)NBATCH * NPART * 5500;    // 2,816,000
  float* hpart = ws + off; off += (size_t)4 * NBATCH * TAUD;        // 2,816,000
  (void)ws_size; (void)in_sizes; (void)n_in; (void)out_size;        // ~31.2 MB total

  double HI = log2(2093.0), LO = log2(32.7);
  float C1 = (float)(HI - LO), C2 = (float)LO;

  k_basis<<<LCONV + 1, 256, 0, stream>>>(G);
  k_f0<<<(NBATCH * NT + 255) / 256, 256, 0, stream>>>(f0n, f0hz, C1, C2);
  k_mlp<<<(NBATCH * NT) / 8, 256, 0, stream>>>(z, W1p, b1p, W2p, b2p,
                                               W1n, b1n, W2n, b2n, amp, nmag);
  k_mean<<<NBATCH, 256, 0, stream>>>(nmag, mmw);
  k_hc<<<LCONV + 1, 256, 0, stream>>>(mmw, G, hh);
  k_scan_top<<<NBATCH * NPART, 256, 0, stream>>>(f0hz, pref4);
  dim3 gh(22, NBATCH, 4);
  k_harm<<<gh, 256, 0, stream>>>(f0hz, amp, pref4, hpart);
  dim3 gc((TAUD + 255) / 256, NBATCH);
  k_conv<<<gc, 256, 0, stream>>>(nz, hh, ynz);
  k_final<<<(NBATCH * TAUD + 255) / 256, 256, 0, stream>>>(hpart, ynz, loud, out);
}